// Round 11
// baseline (153.380 us; speedup 1.0000x reference)
//
#include <hip/hip_runtime.h>
#include <cstdint>

#define THREADS 256
static constexpr int BS   = 4096;
static constexpr int C    = 16384;
static constexpr int D    = 128;
static constexpr int HALF = 2048;   // rows 0..2047 pair with rows 2048..4095
static constexpr int NPOS = 4;
static constexpr int NNEG = 20;
static constexpr int NSEL = 24;
static constexpr int QPT  = 16;     // quads per thread (16*4 = 64 cols)

// Pre-filter: only hashes >= TH enter the per-thread top-2 (top 1/128 of u32;
// ~128 above-thresh candidates/row expected, need <=24; P(shortfall) ~ 0).
// Selection stays EXACT: the cooperative rebuild rescans with NO threshold.
static constexpr uint32_t TH = 0xFE000000u;
// comp32 + OFF64 == full-range 64-bit comp (exact: TH's low 9 bits are 0)
static constexpr uint64_t OFF64 = ((uint64_t)(TH >> 9)) << 14;

// 1-instruction rotate: v_alignbit_b32(x,x,32-r) == rotl(x,r)
__device__ __forceinline__ uint32_t rotl32(uint32_t x, int r) {
  return __builtin_amdgcn_alignbit(x, x, 32 - r);
}

static constexpr uint32_t KS1 = 42u;
static constexpr uint32_t KS2 = 0x1BD11BDAu ^ 42u;   // ks0 = 0

// ---- JAX threefry2x32 (20 rounds), key = PRNGKey(42) = [0, 42] ----
// scalar version (cold/rebuild path)
__device__ __forceinline__ void tf2x32(uint32_t x0, uint32_t x1,
                                       uint32_t& o0, uint32_t& o1) {
  x1 += KS1;
#define TFR(r) { x0 += x1; x1 = rotl32(x1, (r)); x1 ^= x0; }
  TFR(13) TFR(15) TFR(26) TFR(6)
  x0 += KS1; x1 += KS2 + 1u;
  TFR(17) TFR(29) TFR(16) TFR(24)
  x0 += KS2; x1 += 2u;
  TFR(13) TFR(15) TFR(26) TFR(6)
  x1 += KS1 + 3u;
  TFR(17) TFR(29) TFR(16) TFR(24)
  x0 += KS1; x1 += KS2 + 4u;
  TFR(13) TFR(15) TFR(26) TFR(6)
  x0 += KS2; x1 += 5u;
#undef TFR
  o0 = x0; o1 = x1;
}

// 8-wide: 8 independent chains interleaved round-by-round (ILP=8).
// Chains 0-3 hash counters n0+k (quad j), chains 4-7 hash n1+k (quad j+1).
__device__ __forceinline__ void tf8(uint32_t n0, uint32_t n1,
                                    uint32_t (&oa)[8], uint32_t (&ob)[8]) {
  uint32_t x0[8], x1[8];
#pragma unroll
  for (int k = 0; k < 8; ++k) {
    const uint32_t n = (k < 4) ? (n0 + k) : (n1 + (k - 4));
    x0[k] = n; x1[k] = n + (0x2000000u + KS1);
  }
#define R8(r) { _Pragma("unroll") \
  for (int k = 0; k < 8; ++k) { x0[k] += x1[k]; x1[k] = rotl32(x1[k], (r)); x1[k] ^= x0[k]; } }
#define INJ8(a0, a1) { _Pragma("unroll") \
  for (int k = 0; k < 8; ++k) { x0[k] += (a0); x1[k] += (a1); } }
  R8(13) R8(15) R8(26) R8(6)
  INJ8(KS1, KS2 + 1u)
  R8(17) R8(29) R8(16) R8(24)
  INJ8(KS2, 2u)
  R8(13) R8(15) R8(26) R8(6)
  INJ8(0u, KS1 + 3u)
  R8(17) R8(29) R8(16) R8(24)
  INJ8(KS1, KS2 + 4u)
  R8(13) R8(15) R8(26) R8(6)
  INJ8(KS2, 5u)
#undef R8
#undef INJ8
#pragma unroll
  for (int k = 0; k < 8; ++k) { oa[k] = x0[k]; ob[k] = x1[k]; }
}

// full-range 64-bit composite key (rebuild path): larger = better; equal bits
// -> smaller col wins (jax top_k tie-break). Unique per row. 0 = empty.
__device__ __forceinline__ uint64_t mkcomp(uint32_t bits, int c) {
  return (((uint64_t)(bits >> 9) + 1ull) << 14) | (uint64_t)(16383 - c);
}

// branchless thresholded u32 insert (~9 VALU, no label dependency)
__device__ __forceinline__ void filt_ins(uint32_t o, uint32_t invc,
                                         uint32_t& a, uint32_t& b) {
  uint32_t comp = ((((o - TH) >> 9) + 1u) << 14) | invc;
  comp = (o >= TH) ? comp : 0u;
  const uint32_t lo = comp < a ? comp : a;
  a = comp > a ? comp : a;
  b = lo > b ? lo : b;
}

// ---------------- kernel 1: role-split grid ----------------
// blocks with b%9==0 (256 of 2304): extract positives for 16 rows each
//   (pure BW: 256 MB label scan, 8-deep batched int4 loads).
// other 2048 blocks: pure-VALU hash + per-thread top-2 -> cand (NO loads).
// Roles interleave in dispatch order so BW- and VALU-bound blocks coexist
// on each CU from t=0 (separate pipes -> overlap).
__global__ __launch_bounds__(THREADS, 2) void hash_and_pos(
    const int* __restrict__ lab, uint4* __restrict__ cand,
    int4* __restrict__ posIdx) {
  const int b = blockIdx.x;
  const int tid = threadIdx.x;
  const int grp = b / 9;

  if (b % 9 == 0) {
    // ---- extract role: rows grp*16 .. grp*16+15 ----
    __shared__ int cnt;
    __shared__ int buf[8];
    for (int rr = 0; rr < 16; ++rr) {
      const int row = (grp << 4) + rr;
      if (tid == 0) cnt = 0;
      __syncthreads();
      const int4* l4 = reinterpret_cast<const int4*>(lab + (size_t)row * C);
#pragma unroll 1
      for (int h = 0; h < 2; ++h) {
        int4 v[8];
#pragma unroll
        for (int i = 0; i < 8; ++i) v[i] = l4[(h * 8 + i) * THREADS + tid];
#pragma unroll
        for (int i = 0; i < 8; ++i) {
          if (v[i].x | v[i].y | v[i].z | v[i].w) {   // rare
            const int c0 = ((h * 8 + i) * THREADS + tid) << 2;
            if (v[i].x) { int s = atomicAdd(&cnt, 1); if (s < 8) buf[s] = c0; }
            if (v[i].y) { int s = atomicAdd(&cnt, 1); if (s < 8) buf[s] = c0 + 1; }
            if (v[i].z) { int s = atomicAdd(&cnt, 1); if (s < 8) buf[s] = c0 + 2; }
            if (v[i].w) { int s = atomicAdd(&cnt, 1); if (s < 8) buf[s] = c0 + 3; }
          }
        }
      }
      __syncthreads();
      if (tid == 0) {   // exactly 4; sort ascending (jax top_k tie order)
        int a = buf[0], b2 = buf[1], c2 = buf[2], d = buf[3];
#define CSW(x, y) if (x > y) { int t_ = x; x = y; y = t_; }
        CSW(a, b2) CSW(c2, d) CSW(a, c2) CSW(b2, d) CSW(b2, c2)
#undef CSW
        int4 o; o.x = a; o.y = b2; o.z = c2; o.w = d;
        posIdx[row] = o;
      }
    }
    return;
  }

  // ---- hash role: row pair r / r+HALF, zero global loads ----
  const int r = b - grp - 1;           // 0..2047
  const int rbase = r * C;             // threefry x0 base (< 2^25)
  uint32_t L0 = 0, L1 = 0, H0 = 0, H1 = 0;
#pragma unroll 1
  for (int j = 0; j < QPT; j += 2) {
    const int cq0 = (j * THREADS + tid) << 2;
    const int cq1 = cq0 + (THREADS << 2);
    uint32_t oa[8], ob[8];
    tf8((uint32_t)(rbase + cq0), (uint32_t)(rbase + cq1), oa, ob);
    const uint32_t i0 = 16383u - (uint32_t)cq0;
    const uint32_t i1 = 16383u - (uint32_t)cq1;
    filt_ins(oa[0], i0,      L0, L1);  filt_ins(oa[1], i0 - 1u, L0, L1);
    filt_ins(oa[2], i0 - 2u, L0, L1);  filt_ins(oa[3], i0 - 3u, L0, L1);
    filt_ins(oa[4], i1,      L0, L1);  filt_ins(oa[5], i1 - 1u, L0, L1);
    filt_ins(oa[6], i1 - 2u, L0, L1);  filt_ins(oa[7], i1 - 3u, L0, L1);
    filt_ins(ob[0], i0,      H0, H1);  filt_ins(ob[1], i0 - 1u, H0, H1);
    filt_ins(ob[2], i0 - 2u, H0, H1);  filt_ins(ob[3], i0 - 3u, H0, H1);
    filt_ins(ob[4], i1,      H0, H1);  filt_ins(ob[5], i1 - 1u, H0, H1);
    filt_ins(ob[6], i1 - 2u, H0, H1);  filt_ins(ob[7], i1 - 3u, H0, H1);
  }
  uint4 st; st.x = L0; st.y = L1; st.z = H0; st.w = H1;
  cand[(size_t)r * THREADS + tid] = st;
}

// Wave-synchronous top-20-negative selection: pops global-max candidates;
// positive columns are consumed-but-skipped (<=4/row -> <=24 trips total).
// On a thread's cache exhaustion, all 64 lanes cooperatively rescan its 64
// columns (no threshold, no exclusions) for its next comp strictly below
// the last consumed value.
__device__ __forceinline__ void wave_select(
    const uint32_t (*cand)[2], int* selX, int rbase, int hi, int4 p) {
  const int lane = threadIdx.x & 63;
  const int tb = lane << 2;
  const uint64_t laneu = (uint64_t)lane;
#define CVT(x) ((x) ? (uint64_t)(x) + OFF64 : 0ull)
  uint64_t cur0 = CVT(cand[tb + 0][0]), nxt0 = CVT(cand[tb + 0][1]);
  uint64_t cur1 = CVT(cand[tb + 1][0]), nxt1 = CVT(cand[tb + 1][1]);
  uint64_t cur2 = CVT(cand[tb + 2][0]), nxt2 = CVT(cand[tb + 2][1]);
  uint64_t cur3 = CVT(cand[tb + 3][0]), nxt3 = CVT(cand[tb + 3][1]);
#undef CVT
  int got = 0;
#pragma unroll 1
  for (int it = 0; it < NSEL && got < NNEG; ++it) {
    uint64_t m = (cur0 << 8) | laneu;
    uint64_t t = (cur1 << 8) | 0x40ull | laneu; if (t > m) m = t;
    t = (cur2 << 8) | 0x80ull | laneu;          if (t > m) m = t;
    t = (cur3 << 8) | 0xC0ull | laneu;          if (t > m) m = t;
#pragma unroll
    for (int o = 32; o; o >>= 1) {
      const uint64_t y = (uint64_t)__shfl_xor((unsigned long long)m, o, 64);
      if (y > m) m = y;
    }
    const int col = 16383 - (int)((m >> 8) & 0x3FFFull);
    const bool isPos = (col == p.x) || (col == p.y) || (col == p.z) || (col == p.w);
    if (!isPos) {
      if (lane == 0) selX[NPOS + got] = col;
      ++got;
    }
    const int owner = (int)(m & 63ull);
    const int slot  = (int)((m >> 6) & 3ull);
    const uint64_t bound = m >> 8;
    const uint64_t mynxt = slot == 0 ? nxt0 : slot == 1 ? nxt1
                         : slot == 2 ? nxt2 : nxt3;
    const uint64_t ownnxt =
        (uint64_t)__shfl((unsigned long long)mynxt, owner, 64);
    if (ownnxt) {                       // wave-uniform branch
      if (lane == owner) {
        if      (slot == 0) { cur0 = ownnxt; nxt0 = 0; }
        else if (slot == 1) { cur1 = ownnxt; nxt1 = 0; }
        else if (slot == 2) { cur2 = ownnxt; nxt2 = 0; }
        else                { cur3 = ownnxt; nxt3 = 0; }
      }
    } else {                            // cooperative rebuild (rare)
      const int thr = (owner << 2) | slot;
      const int col2 = (((lane >> 2) * THREADS + thr) << 2) + (lane & 3);
      uint32_t o0, o1;
      tf2x32((uint32_t)(rbase + col2), (uint32_t)(rbase + col2) + 0x2000000u, o0, o1);
      uint64_t v = mkcomp(hi ? o1 : o0, col2);
      if (v >= bound) v = 0;
#pragma unroll
      for (int o = 32; o; o >>= 1) {
        const uint64_t y = (uint64_t)__shfl_xor((unsigned long long)v, o, 64);
        if (y > v) v = y;
      }
      if (lane == owner) {
        if      (slot == 0) cur0 = v;
        else if (slot == 1) cur1 = v;
        else if (slot == 2) cur2 = v;
        else                cur3 = v;
      }
    }
  }
}

// ---------------- kernel 2: select + sim + BCE ----------------
__global__ __launch_bounds__(THREADS, 2) void select_sim(
    const float* __restrict__ feat, const float* __restrict__ proto,
    const uint4* __restrict__ cand, const int4* __restrict__ posIdx,
    float* __restrict__ row_ws) {
  __shared__ uint32_t candL[THREADS][2];
  __shared__ uint32_t candH[THREADS][2];
  __shared__ int selL[NSEL], selH[NSEL];
  __shared__ float ffL[D], ffH[D];
  __shared__ float normL, normH;
  __shared__ float bces[2 * NSEL];

  const int tid = threadIdx.x;
  const int r = blockIdx.x;
  const int rbase = r * C;

  const uint4 cd = cand[(size_t)r * THREADS + tid];
  candL[tid][0] = cd.x; candL[tid][1] = cd.y;
  candH[tid][0] = cd.z; candH[tid][1] = cd.w;
  const int4 pL = posIdx[r];
  const int4 pH = posIdx[r + HALF];
  if (tid == 0) { selL[0] = pL.x; selL[1] = pL.y; selL[2] = pL.z; selL[3] = pL.w; }
  if (tid == 1) { selH[0] = pH.x; selH[1] = pH.y; selH[2] = pH.z; selH[3] = pH.w; }
  __syncthreads();

  const int wv = tid >> 6;
  if (wv == 0) {
    wave_select(candL, selL, rbase, 0, pL);
  } else if (wv == 1) {
    wave_select(candH, selH, rbase, 1, pH);
  } else if (wv == 2) {
    const int l = tid & 63;
    const float a = feat[(size_t)r * D + l];
    const float b = feat[(size_t)r * D + 64 + l];
    ffL[l] = a; ffL[64 + l] = b;
    float s = a * a + b * b;
#pragma unroll
    for (int o = 32; o; o >>= 1) s += __shfl_xor(s, o, 64);
    if (l == 0) normL = s;
  } else {
    const int l = tid & 63;
    const float a = feat[((size_t)r + HALF) * D + l];
    const float b = feat[((size_t)r + HALF) * D + 64 + l];
    ffH[l] = a; ffH[64 + l] = b;
    float s = a * a + b * b;
#pragma unroll
    for (int o = 32; o; o >>= 1) s += __shfl_xor(s, o, 64);
    if (l == 0) normH = s;
  }
  __syncthreads();

  if (tid < 4 * 2 * NSEL) {
    const int ci = tid >> 2;            // 0..47
    const int k  = tid & 3;
    const bool isH = ci >= NSEL;
    const int g = isH ? ci - NSEL : ci;
    const int c = isH ? selH[g] : selL[g];
    const float* ff = isH ? ffH : ffL;
    const float4* pc = reinterpret_cast<const float4*>(proto + (size_t)c * D);
    float fp = 0.f, pp = 0.f;
#pragma unroll
    for (int qq = 0; qq < 8; ++qq) {
      const float4 pv = pc[k * 8 + qq];
      const int d0 = k * 32 + qq * 4;
      fp += ff[d0] * pv.x + ff[d0 + 1] * pv.y + ff[d0 + 2] * pv.z + ff[d0 + 3] * pv.w;
      pp += pv.x * pv.x + pv.y * pv.y + pv.z * pv.z + pv.w * pv.w;
    }
    fp += __shfl_xor(fp, 1, 64); pp += __shfl_xor(pp, 1, 64);
    fp += __shfl_xor(fp, 2, 64); pp += __shfl_xor(pp, 2, 64);
    if (k == 0) {
      const float x = (isH ? normH : normL) * pp;
      float rn = rsqrtf(x);
      rn = rn * (1.5f - 0.5f * x * rn * rn);   // 1 NR step for accuracy
      const float l = fp * rn * 10.0f;          // /TEMP, TEMP=0.1
      const float tgt = (g < NPOS) ? 0.25f : 0.0f;
      bces[ci] = fmaxf(l, 0.f) - l * tgt + __logf(1.0f + __expf(-fabsf(l)));
    }
  }
  __syncthreads();
  if (tid < 2) {
    float s = 0.f;
    const int base = tid * NSEL;
#pragma unroll
    for (int i = 0; i < NSEL; ++i) s += bces[base + i];
    row_ws[tid ? (r + HALF) : r] = s * (1.0f / NSEL);
  }
}

__global__ __launch_bounds__(THREADS) void supcon_reduce(
    const float* __restrict__ ws, float* __restrict__ out) {
  __shared__ float red[THREADS];
  const int tid = threadIdx.x;
  float s = 0.f;
#pragma unroll
  for (int j = 0; j < BS / THREADS; ++j) s += ws[j * THREADS + tid];
  red[tid] = s;
  __syncthreads();
  for (int o = THREADS / 2; o > 0; o >>= 1) {
    if (tid < o) red[tid] += red[tid + o];
    __syncthreads();
  }
  if (tid == 0) out[0] = red[0] * (1.0f / BS);
}

extern "C" void kernel_launch(void* const* d_in, const int* in_sizes, int n_in,
                              void* d_out, int out_size, void* d_ws, size_t ws_size,
                              hipStream_t stream) {
  (void)in_sizes; (void)n_in; (void)out_size; (void)ws_size;
  const float* feat  = (const float*)d_in[0];
  const float* proto = (const float*)d_in[1];
  const int*   lab   = (const int*)d_in[2];
  float* out = (float*)d_out;
  // ws layout: [0,16K): row_ws float[4096]; [16K,80K): posIdx int4[4096];
  //            [128K,128K+8M): cand uint4[2048*256]
  float* ws     = (float*)d_ws;
  int4*  posIdx = (int4*)((char*)d_ws + (16 << 10));
  uint4* cand   = (uint4*)((char*)d_ws + (128 << 10));

  hash_and_pos<<<dim3(HALF + HALF / 8), dim3(THREADS), 0, stream>>>(lab, cand, posIdx);
  select_sim  <<<dim3(HALF), dim3(THREADS), 0, stream>>>(feat, proto, cand, posIdx, ws);
  supcon_reduce<<<dim3(1), dim3(THREADS), 0, stream>>>(ws, out);
}

// Round 12
// 117.888 us; speedup vs baseline: 1.3011x; 1.3011x over previous
//
#include <hip/hip_runtime.h>
#include <cstdint>

#define THREADS 256
static constexpr int BS   = 4096;
static constexpr int C    = 16384;
static constexpr int D    = 128;
static constexpr int HALF = 2048;   // rows 0..2047 pair with rows 2048..4095
static constexpr int NPOS = 4;
static constexpr int NNEG = 20;
static constexpr int NSEL = 24;
static constexpr int QPT  = 16;     // quads per thread (16*4 = 64 cols)

// Pre-filter: only hashes >= TH enter the per-thread top-2 (top 1/128 of u32;
// ~128 above-thresh candidates/row expected, need <=24; P(shortfall) ~ 0).
// Selection stays EXACT: the cooperative rebuild rescans with NO threshold.
static constexpr uint32_t TH = 0xFE000000u;
// comp32 + OFF64 == full-range 64-bit comp (exact: TH's low 9 bits are 0)
static constexpr uint64_t OFF64 = ((uint64_t)(TH >> 9)) << 14;

// 1-instruction rotate: v_alignbit_b32(x,x,32-r) == rotl(x,r)
__device__ __forceinline__ uint32_t rotl32(uint32_t x, int r) {
  return __builtin_amdgcn_alignbit(x, x, 32 - r);
}

static constexpr uint32_t KS1 = 42u;
static constexpr uint32_t KS2 = 0x1BD11BDAu ^ 42u;   // ks0 = 0

// ---- JAX threefry2x32 (20 rounds), key = PRNGKey(42) = [0, 42] ----
// scalar version (cold/rebuild path)
__device__ __forceinline__ void tf2x32(uint32_t x0, uint32_t x1,
                                       uint32_t& o0, uint32_t& o1) {
  x1 += KS1;
#define TFR(r) { x0 += x1; x1 = rotl32(x1, (r)); x1 ^= x0; }
  TFR(13) TFR(15) TFR(26) TFR(6)
  x0 += KS1; x1 += KS2 + 1u;
  TFR(17) TFR(29) TFR(16) TFR(24)
  x0 += KS2; x1 += 2u;
  TFR(13) TFR(15) TFR(26) TFR(6)
  x1 += KS1 + 3u;
  TFR(17) TFR(29) TFR(16) TFR(24)
  x0 += KS1; x1 += KS2 + 4u;
  TFR(13) TFR(15) TFR(26) TFR(6)
  x0 += KS2; x1 += 5u;
#undef TFR
  o0 = x0; o1 = x1;
}

// 16-wide: 16 independent chains interleaved round-by-round (ILP=16).
// Chain m = q*4+k hashes counter n0 + q*1024 + k (quad j+q, lane-col k).
__device__ __forceinline__ void tf16(uint32_t n0, uint32_t (&oa)[16],
                                     uint32_t (&ob)[16]) {
  uint32_t x0[16], x1[16];
#pragma unroll
  for (int m = 0; m < 16; ++m) {
    const uint32_t n = n0 + (uint32_t)((m >> 2) << 10) + (uint32_t)(m & 3);
    x0[m] = n; x1[m] = n + (0x2000000u + KS1);
  }
#define R16(r) { _Pragma("unroll") \
  for (int m = 0; m < 16; ++m) { x0[m] += x1[m]; x1[m] = rotl32(x1[m], (r)); x1[m] ^= x0[m]; } }
#define INJ16(a0, a1) { _Pragma("unroll") \
  for (int m = 0; m < 16; ++m) { x0[m] += (a0); x1[m] += (a1); } }
  R16(13) R16(15) R16(26) R16(6)
  INJ16(KS1, KS2 + 1u)
  R16(17) R16(29) R16(16) R16(24)
  INJ16(KS2, 2u)
  R16(13) R16(15) R16(26) R16(6)
  INJ16(0u, KS1 + 3u)
  R16(17) R16(29) R16(16) R16(24)
  INJ16(KS1, KS2 + 4u)
  R16(13) R16(15) R16(26) R16(6)
  INJ16(KS2, 5u)
#undef R16
#undef INJ16
#pragma unroll
  for (int m = 0; m < 16; ++m) { oa[m] = x0[m]; ob[m] = x1[m]; }
}

// full-range 64-bit composite key (rebuild path): larger = better; equal bits
// -> smaller col wins (jax top_k tie-break). Unique per row. 0 = empty.
__device__ __forceinline__ uint64_t mkcomp(uint32_t bits, int c) {
  return (((uint64_t)(bits >> 9) + 1ull) << 14) | (uint64_t)(16383 - c);
}

// branchless thresholded u32 insert (~9 VALU, no label dependency)
__device__ __forceinline__ void filt_ins(uint32_t o, uint32_t invc,
                                         uint32_t& a, uint32_t& b) {
  uint32_t comp = ((((o - TH) >> 9) + 1u) << 14) | invc;
  comp = (o >= TH) ? comp : 0u;
  const uint32_t lo = comp < a ? comp : a;
  a = comp > a ? comp : a;
  b = lo > b ? lo : b;
}

// ---------------- kernel 1: labels + hash + per-thread top-2 ----------------
// Writes cand[r*256+tid] = {L0,L1,H0,H1} and posIdx[r*2+{0,1}] (sorted).
// Positives are NOT excluded from the candidate stream (removed at selection).
// waves_per_eu(2,4): cap the occupancy target so the allocator keeps all 16
// threefry chains live (~100 VGPR) instead of squeezing to ~32 and
// serializing the chains (rounds 6-10: VGPR=32, VALUBusy~70%, 2.5x floor).
__global__ void __launch_bounds__(THREADS)
__attribute__((amdgpu_waves_per_eu(2, 4)))
hash_topk(const int* __restrict__ lab, uint4* __restrict__ cand,
          int4* __restrict__ posIdx) {
  __shared__ int posCnt[2];
  __shared__ int posBuf[2][4];
  const int tid = threadIdx.x;
  const int r = blockIdx.x;
  const int rbase = r * C;

  if (tid < 2) posCnt[tid] = 0;
  __syncthreads();

  const int4* labL4 = reinterpret_cast<const int4*>(lab + (size_t)rbase);
  const int4* labH4 = reinterpret_cast<const int4*>(lab + ((size_t)r + HALF) * C);
  uint32_t L0 = 0, L1 = 0, H0 = 0, H1 = 0;

#define CAP(V, S, CQ) \
  if (V.x | V.y | V.z | V.w) { \
    if (V.x) { int s = atomicAdd(&posCnt[S], 1); if (s < 4) posBuf[S][s] = (CQ); }     \
    if (V.y) { int s = atomicAdd(&posCnt[S], 1); if (s < 4) posBuf[S][s] = (CQ) + 1; } \
    if (V.z) { int s = atomicAdd(&posCnt[S], 1); if (s < 4) posBuf[S][s] = (CQ) + 2; } \
    if (V.w) { int s = atomicAdd(&posCnt[S], 1); if (s < 4) posBuf[S][s] = (CQ) + 3; } \
  }

#pragma unroll 1
  for (int j = 0; j < QPT; j += 4) {
    // issue all 8 label loads up-front; consumed after ~1400 VALU ops below
    int4 vL[4], vH[4];
#pragma unroll
    for (int i = 0; i < 4; ++i) {
      vL[i] = labL4[(j + i) * THREADS + tid];
      vH[i] = labH4[(j + i) * THREADS + tid];
    }
    const int cq0 = (j * THREADS + tid) << 2;   // quad j+i at cq0 + i*1024
    uint32_t oa[16], ob[16];
    tf16((uint32_t)(rbase + cq0), oa, ob);
#pragma unroll
    for (int q = 0; q < 4; ++q) {
      const uint32_t iq = 16383u - (uint32_t)(cq0 + (q << 10));
#pragma unroll
      for (int k = 0; k < 4; ++k) {
        filt_ins(oa[q * 4 + k], iq - (uint32_t)k, L0, L1);
        filt_ins(ob[q * 4 + k], iq - (uint32_t)k, H0, H1);
      }
    }
#pragma unroll
    for (int i = 0; i < 4; ++i) {
      const int cq = cq0 + (i << 10);
      CAP(vL[i], 0, cq)
      CAP(vH[i], 1, cq)
    }
  }
#undef CAP

  uint4 st; st.x = L0; st.y = L1; st.z = H0; st.w = H1;
  cand[(size_t)r * THREADS + tid] = st;
  __syncthreads();
  if (tid < 2) {   // sort 4 positive cols ascending (jax top_k tie order)
    int a = posBuf[tid][0], b2 = posBuf[tid][1], c2 = posBuf[tid][2], d = posBuf[tid][3];
#define CSW(x, y) if (x > y) { int t_ = x; x = y; y = t_; }
    CSW(a, b2) CSW(c2, d) CSW(a, c2) CSW(b2, d) CSW(b2, c2)
#undef CSW
    int4 o; o.x = a; o.y = b2; o.z = c2; o.w = d;
    posIdx[r * 2 + tid] = o;
  }
}

// Wave-synchronous top-20-negative selection: pops global-max candidates;
// positive columns are consumed-but-skipped (<=4/row -> <=24 trips total).
// On a thread's cache exhaustion, all 64 lanes cooperatively rescan its 64
// columns (no threshold, no exclusions) for its next comp strictly below
// the last consumed value.
__device__ __forceinline__ void wave_select(
    const uint32_t (*cand)[2], int* selX, int rbase, int hi, int4 p) {
  const int lane = threadIdx.x & 63;
  const int tb = lane << 2;
  const uint64_t laneu = (uint64_t)lane;
#define CVT(x) ((x) ? (uint64_t)(x) + OFF64 : 0ull)
  uint64_t cur0 = CVT(cand[tb + 0][0]), nxt0 = CVT(cand[tb + 0][1]);
  uint64_t cur1 = CVT(cand[tb + 1][0]), nxt1 = CVT(cand[tb + 1][1]);
  uint64_t cur2 = CVT(cand[tb + 2][0]), nxt2 = CVT(cand[tb + 2][1]);
  uint64_t cur3 = CVT(cand[tb + 3][0]), nxt3 = CVT(cand[tb + 3][1]);
#undef CVT
  int got = 0;
#pragma unroll 1
  for (int it = 0; it < NSEL && got < NNEG; ++it) {
    uint64_t m = (cur0 << 8) | laneu;
    uint64_t t = (cur1 << 8) | 0x40ull | laneu; if (t > m) m = t;
    t = (cur2 << 8) | 0x80ull | laneu;          if (t > m) m = t;
    t = (cur3 << 8) | 0xC0ull | laneu;          if (t > m) m = t;
#pragma unroll
    for (int o = 32; o; o >>= 1) {
      const uint64_t y = (uint64_t)__shfl_xor((unsigned long long)m, o, 64);
      if (y > m) m = y;
    }
    const int col = 16383 - (int)((m >> 8) & 0x3FFFull);
    const bool isPos = (col == p.x) || (col == p.y) || (col == p.z) || (col == p.w);
    if (!isPos) {
      if (lane == 0) selX[NPOS + got] = col;
      ++got;
    }
    const int owner = (int)(m & 63ull);
    const int slot  = (int)((m >> 6) & 3ull);
    const uint64_t bound = m >> 8;
    const uint64_t mynxt = slot == 0 ? nxt0 : slot == 1 ? nxt1
                         : slot == 2 ? nxt2 : nxt3;
    const uint64_t ownnxt =
        (uint64_t)__shfl((unsigned long long)mynxt, owner, 64);
    if (ownnxt) {                       // wave-uniform branch
      if (lane == owner) {
        if      (slot == 0) { cur0 = ownnxt; nxt0 = 0; }
        else if (slot == 1) { cur1 = ownnxt; nxt1 = 0; }
        else if (slot == 2) { cur2 = ownnxt; nxt2 = 0; }
        else                { cur3 = ownnxt; nxt3 = 0; }
      }
    } else {                            // cooperative rebuild (rare)
      const int thr = (owner << 2) | slot;
      const int col2 = (((lane >> 2) * THREADS + thr) << 2) + (lane & 3);
      uint32_t o0, o1;
      tf2x32((uint32_t)(rbase + col2), (uint32_t)(rbase + col2) + 0x2000000u, o0, o1);
      uint64_t v = mkcomp(hi ? o1 : o0, col2);
      if (v >= bound) v = 0;
#pragma unroll
      for (int o = 32; o; o >>= 1) {
        const uint64_t y = (uint64_t)__shfl_xor((unsigned long long)v, o, 64);
        if (y > v) v = y;
      }
      if (lane == owner) {
        if      (slot == 0) cur0 = v;
        else if (slot == 1) cur1 = v;
        else if (slot == 2) cur2 = v;
        else                cur3 = v;
      }
    }
  }
}

// ---------------- kernel 2: select + sim + BCE ----------------
__global__ __launch_bounds__(THREADS, 2) void select_sim(
    const float* __restrict__ feat, const float* __restrict__ proto,
    const uint4* __restrict__ cand, const int4* __restrict__ posIdx,
    float* __restrict__ row_ws) {
  __shared__ uint32_t candL[THREADS][2];
  __shared__ uint32_t candH[THREADS][2];
  __shared__ int selL[NSEL], selH[NSEL];
  __shared__ float ffL[D], ffH[D];
  __shared__ float normL, normH;
  __shared__ float bces[2 * NSEL];

  const int tid = threadIdx.x;
  const int r = blockIdx.x;
  const int rbase = r * C;

  const uint4 cd = cand[(size_t)r * THREADS + tid];
  candL[tid][0] = cd.x; candL[tid][1] = cd.y;
  candH[tid][0] = cd.z; candH[tid][1] = cd.w;
  const int4 pL = posIdx[r * 2];
  const int4 pH = posIdx[r * 2 + 1];
  if (tid == 0) { selL[0] = pL.x; selL[1] = pL.y; selL[2] = pL.z; selL[3] = pL.w; }
  if (tid == 1) { selH[0] = pH.x; selH[1] = pH.y; selH[2] = pH.z; selH[3] = pH.w; }
  __syncthreads();

  const int wv = tid >> 6;
  if (wv == 0) {
    wave_select(candL, selL, rbase, 0, pL);
  } else if (wv == 1) {
    wave_select(candH, selH, rbase, 1, pH);
  } else if (wv == 2) {
    const int l = tid & 63;
    const float a = feat[(size_t)r * D + l];
    const float b = feat[(size_t)r * D + 64 + l];
    ffL[l] = a; ffL[64 + l] = b;
    float s = a * a + b * b;
#pragma unroll
    for (int o = 32; o; o >>= 1) s += __shfl_xor(s, o, 64);
    if (l == 0) normL = s;
  } else {
    const int l = tid & 63;
    const float a = feat[((size_t)r + HALF) * D + l];
    const float b = feat[((size_t)r + HALF) * D + 64 + l];
    ffH[l] = a; ffH[64 + l] = b;
    float s = a * a + b * b;
#pragma unroll
    for (int o = 32; o; o >>= 1) s += __shfl_xor(s, o, 64);
    if (l == 0) normH = s;
  }
  __syncthreads();

  if (tid < 4 * 2 * NSEL) {
    const int ci = tid >> 2;            // 0..47
    const int k  = tid & 3;
    const bool isH = ci >= NSEL;
    const int g = isH ? ci - NSEL : ci;
    const int c = isH ? selH[g] : selL[g];
    const float* ff = isH ? ffH : ffL;
    const float4* pc = reinterpret_cast<const float4*>(proto + (size_t)c * D);
    float fp = 0.f, pp = 0.f;
#pragma unroll
    for (int qq = 0; qq < 8; ++qq) {
      const float4 pv = pc[k * 8 + qq];
      const int d0 = k * 32 + qq * 4;
      fp += ff[d0] * pv.x + ff[d0 + 1] * pv.y + ff[d0 + 2] * pv.z + ff[d0 + 3] * pv.w;
      pp += pv.x * pv.x + pv.y * pv.y + pv.z * pv.z + pv.w * pv.w;
    }
    fp += __shfl_xor(fp, 1, 64); pp += __shfl_xor(pp, 1, 64);
    fp += __shfl_xor(fp, 2, 64); pp += __shfl_xor(pp, 2, 64);
    if (k == 0) {
      const float x = (isH ? normH : normL) * pp;
      float rn = rsqrtf(x);
      rn = rn * (1.5f - 0.5f * x * rn * rn);   // 1 NR step for accuracy
      const float l = fp * rn * 10.0f;          // /TEMP, TEMP=0.1
      const float tgt = (g < NPOS) ? 0.25f : 0.0f;
      bces[ci] = fmaxf(l, 0.f) - l * tgt + __logf(1.0f + __expf(-fabsf(l)));
    }
  }
  __syncthreads();
  if (tid < 2) {
    float s = 0.f;
    const int base = tid * NSEL;
#pragma unroll
    for (int i = 0; i < NSEL; ++i) s += bces[base + i];
    row_ws[tid ? (r + HALF) : r] = s * (1.0f / NSEL);
  }
}

__global__ __launch_bounds__(THREADS) void supcon_reduce(
    const float* __restrict__ ws, float* __restrict__ out) {
  __shared__ float red[THREADS];
  const int tid = threadIdx.x;
  float s = 0.f;
#pragma unroll
  for (int j = 0; j < BS / THREADS; ++j) s += ws[j * THREADS + tid];
  red[tid] = s;
  __syncthreads();
  for (int o = THREADS / 2; o > 0; o >>= 1) {
    if (tid < o) red[tid] += red[tid + o];
    __syncthreads();
  }
  if (tid == 0) out[0] = red[0] * (1.0f / BS);
}

extern "C" void kernel_launch(void* const* d_in, const int* in_sizes, int n_in,
                              void* d_out, int out_size, void* d_ws, size_t ws_size,
                              hipStream_t stream) {
  (void)in_sizes; (void)n_in; (void)out_size; (void)ws_size;
  const float* feat  = (const float*)d_in[0];
  const float* proto = (const float*)d_in[1];
  const int*   lab   = (const int*)d_in[2];
  float* out = (float*)d_out;
  // ws layout: [0,16K): row_ws float[4096]; [16K,128K): posIdx int4[4096];
  //            [128K,128K+8M): cand uint4[2048*256]
  float* ws     = (float*)d_ws;
  int4*  posIdx = (int4*)((char*)d_ws + (16 << 10));
  uint4* cand   = (uint4*)((char*)d_ws + (128 << 10));

  hash_topk <<<dim3(HALF), dim3(THREADS), 0, stream>>>(lab, cand, posIdx);
  select_sim<<<dim3(HALF), dim3(THREADS), 0, stream>>>(feat, proto, cand, posIdx, ws);
  supcon_reduce<<<dim3(1), dim3(THREADS), 0, stream>>>(ws, out);
}

// Round 13
// 111.022 us; speedup vs baseline: 1.3815x; 1.0618x over previous
//
#include <hip/hip_runtime.h>
#include <cstdint>

static constexpr int T1   = 512;    // hash kernel block size (8 waves)
static constexpr int T2   = 256;    // select kernel block size
static constexpr int BS   = 4096;
static constexpr int C    = 16384;
static constexpr int D    = 128;
static constexpr int HALF = 2048;   // rows 0..2047 pair with rows 2048..4095
static constexpr int NPOS = 4;
static constexpr int NNEG = 20;
static constexpr int NSEL = 24;
static constexpr int QPT1 = 8;      // int4 quads per thread per row (32 cols)

// Pre-filter threshold: top 1/128 of u32 (~128 candidates/row, need <=24).
// Below-TH elements produce small nonzero "fake" comps (< 32768) that are
// strictly below every real d>=1 candidate and are never popped; selection
// stays exact (rebuild rescans with no threshold; absmax=0 re-validates).
static constexpr uint32_t TH = 0xFE000000u;
// comp32 + OFF64 == full-range 64-bit comp (exact: TH's low 9 bits are 0)
static constexpr uint64_t OFF64 = ((uint64_t)(TH >> 9)) << 14;

__device__ __forceinline__ uint32_t rotl32(uint32_t x, int r) {
  return __builtin_amdgcn_alignbit(x, x, 32 - r);   // 1 instr
}

static constexpr uint32_t KS1 = 42u;
static constexpr uint32_t KS2 = 0x1BD11BDAu ^ 42u;   // ks0 = 0

// ---- JAX threefry2x32 (20 rounds), key = PRNGKey(42) = [0, 42] ----
__device__ __forceinline__ void tf2x32(uint32_t x0, uint32_t x1,
                                       uint32_t& o0, uint32_t& o1) {
  x1 += KS1;
#define TFR(r) { x0 += x1; x1 = rotl32(x1, (r)); x1 ^= x0; }
  TFR(13) TFR(15) TFR(26) TFR(6)
  x0 += KS1; x1 += KS2 + 1u;
  TFR(17) TFR(29) TFR(16) TFR(24)
  x0 += KS2; x1 += 2u;
  TFR(13) TFR(15) TFR(26) TFR(6)
  x1 += KS1 + 3u;
  TFR(17) TFR(29) TFR(16) TFR(24)
  x0 += KS1; x1 += KS2 + 4u;
  TFR(13) TFR(15) TFR(26) TFR(6)
  x0 += KS2; x1 += 5u;
#undef TFR
  o0 = x0; o1 = x1;
}

// 8 independent chains, round-interleaved (ILP=8). Chains 0-3: quad j
// (counter n0+k), chains 4-7: quad j+1 (n1 = n0 + 2048, 512-thread stride).
__device__ __forceinline__ void tf8(uint32_t n0, uint32_t n1,
                                    uint32_t (&oa)[8], uint32_t (&ob)[8]) {
  uint32_t x0[8], x1[8];
#pragma unroll
  for (int k = 0; k < 8; ++k) {
    const uint32_t n = (k < 4) ? (n0 + k) : (n1 + (k - 4));
    x0[k] = n; x1[k] = n + (0x2000000u + KS1);
  }
#define R8(r) { _Pragma("unroll") \
  for (int k = 0; k < 8; ++k) { x0[k] += x1[k]; x1[k] = rotl32(x1[k], (r)); x1[k] ^= x0[k]; } }
#define INJ8(a0, a1) { _Pragma("unroll") \
  for (int k = 0; k < 8; ++k) { x0[k] += (a0); x1[k] += (a1); } }
  R8(13) R8(15) R8(26) R8(6)
  INJ8(KS1, KS2 + 1u)
  R8(17) R8(29) R8(16) R8(24)
  INJ8(KS2, 2u)
  R8(13) R8(15) R8(26) R8(6)
  INJ8(0u, KS1 + 3u)
  R8(17) R8(29) R8(16) R8(24)
  INJ8(KS1, KS2 + 4u)
  R8(13) R8(15) R8(26) R8(6)
  INJ8(KS2, 5u)
#undef R8
#undef INJ8
#pragma unroll
  for (int k = 0; k < 8; ++k) { oa[k] = x0[k]; ob[k] = x1[k]; }
}

// full-range 64-bit composite key (rebuild path): larger = better; equal bits
// -> smaller col wins (jax top_k tie-break). Unique per row.
__device__ __forceinline__ uint64_t mkcomp(uint32_t bits, int c) {
  return (((uint64_t)(bits >> 9) + 1ull) << 14) | (uint64_t)(16383 - c);
}

// 7-op thresholded insert: saturate at TH (max+sub), d = t>>9,
// comp = d<<14 + Ke where Ke = 32767 - col. Real candidates (o>=TH) give the
// exact previous comp ((d+1)<<14 | invc); below-TH gives the small fake Ke.
__device__ __forceinline__ void filt_ins(uint32_t o, uint32_t Ke,
                                         uint32_t& a, uint32_t& b) {
  const uint32_t t = ((o > TH) ? o : TH) - TH;       // v_max_u32 + v_sub
  const uint32_t comp = ((t >> 9) << 14) + Ke;       // v_lshr + v_lshl_add
  const uint32_t lo = comp < a ? comp : a;
  a = comp > a ? comp : a;
  b = lo > b ? lo : b;
}

// ---------------- kernel 1: labels + hash + per-thread top-2 ----------------
// 512 threads, 32 cols/thread. Writes cand[r*512+tid] = {L0,L1,H0,H1} and
// posIdx[r*2+{0,1}]. Positives are NOT excluded here (skipped at selection).
__global__ __launch_bounds__(T1) void hash_topk(
    const int* __restrict__ lab, uint4* __restrict__ cand,
    int4* __restrict__ posIdx) {
  __shared__ int posCnt[2];
  __shared__ int posBuf[2][4];
  const int tid = threadIdx.x;
  const int r = blockIdx.x;
  const int rbase = r * C;

  if (tid < 2) posCnt[tid] = 0;
  __syncthreads();

  const int4* labL4 = reinterpret_cast<const int4*>(lab + (size_t)rbase);
  const int4* labH4 = reinterpret_cast<const int4*>(lab + ((size_t)r + HALF) * C);
  uint32_t L0 = 0, L1 = 0, H0 = 0, H1 = 0;

#define CAP(V, S, CQ) \
  if (V.x | V.y | V.z | V.w) { \
    if (V.x) { int s = atomicAdd(&posCnt[S], 1); if (s < 4) posBuf[S][s] = (CQ); }     \
    if (V.y) { int s = atomicAdd(&posCnt[S], 1); if (s < 4) posBuf[S][s] = (CQ) + 1; } \
    if (V.z) { int s = atomicAdd(&posCnt[S], 1); if (s < 4) posBuf[S][s] = (CQ) + 2; } \
    if (V.w) { int s = atomicAdd(&posCnt[S], 1); if (s < 4) posBuf[S][s] = (CQ) + 3; } \
  }

#pragma unroll 1
  for (int j = 0; j < QPT1; j += 2) {
    // loads issued up-front; hash (~700 VALU) runs before CAP consumes them
    const int4 vL0 = labL4[j * T1 + tid];
    const int4 vL1 = labL4[(j + 1) * T1 + tid];
    const int4 vH0 = labH4[j * T1 + tid];
    const int4 vH1 = labH4[(j + 1) * T1 + tid];
    const int cq0 = (j * T1 + tid) << 2;          // quad j; quad j+1 at +2048
    uint32_t oa[8], ob[8];
    tf8((uint32_t)(rbase + cq0), (uint32_t)(rbase + cq0 + 2048), oa, ob);
    const uint32_t ke0 = 32767u - (uint32_t)cq0;
    const uint32_t ke1 = ke0 - 2048u;
#pragma unroll
    for (int k = 0; k < 4; ++k) {
      filt_ins(oa[k],     ke0 - (uint32_t)k, L0, L1);
      filt_ins(oa[4 + k], ke1 - (uint32_t)k, L0, L1);
      filt_ins(ob[k],     ke0 - (uint32_t)k, H0, H1);
      filt_ins(ob[4 + k], ke1 - (uint32_t)k, H0, H1);
    }
    CAP(vL0, 0, cq0) CAP(vL1, 0, cq0 + 2048)
    CAP(vH0, 1, cq0) CAP(vH1, 1, cq0 + 2048)
  }
#undef CAP

  uint4 st; st.x = L0; st.y = L1; st.z = H0; st.w = H1;
  cand[(size_t)r * T1 + tid] = st;
  __syncthreads();
  if (tid < 2) {   // sort 4 positive cols ascending (jax top_k tie order)
    int a = posBuf[tid][0], b2 = posBuf[tid][1], c2 = posBuf[tid][2], d = posBuf[tid][3];
#define CSW(x, y) if (x > y) { int t_ = x; x = y; y = t_; }
    CSW(a, b2) CSW(c2, d) CSW(a, c2) CSW(b2, d) CSW(b2, c2)
#undef CSW
    int4 o; o.x = a; o.y = b2; o.z = c2; o.w = d;
    posIdx[r * 2 + tid] = o;
  }
}

// Wave-synchronous top-20-negative selection over 512 depth-2 lists
// (8 lists per lane, statically indexed). Positives consumed-but-skipped.
// On list exhaustion (promotion wrote nxt=0), lanes 0..31 cooperatively
// rescan that thread's 32 columns (true comps, no threshold) for the next
// value strictly below the last consumed.
__device__ __forceinline__ void wave_select8(
    const uint32_t (*cd)[2], int* selX, int rbase, int hi, int4 p) {
  const int lane = threadIdx.x & 63;
  const int tb = lane << 3;
  const uint64_t laneu = (uint64_t)lane;
  uint64_t cur[8], nxt[8];
#pragma unroll
  for (int s = 0; s < 8; ++s) {
    cur[s] = (uint64_t)cd[tb + s][0] + OFF64;
    nxt[s] = (uint64_t)cd[tb + s][1] + OFF64;
  }
  int got = 0;
#pragma unroll 1
  for (int it = 0; it < NSEL && got < NNEG; ++it) {
    uint64_t m = 0;
#pragma unroll
    for (int s = 0; s < 8; ++s) {
      const uint64_t t = (cur[s] << 9) | ((uint64_t)s << 6) | laneu;
      if (t > m) m = t;
    }
#pragma unroll
    for (int o = 32; o; o >>= 1) {
      const uint64_t y = (uint64_t)__shfl_xor((unsigned long long)m, o, 64);
      if (y > m) m = y;
    }
    const int col = 16383 - (int)((m >> 9) & 0x3FFFull);
    const bool isPos = (col == p.x) || (col == p.y) || (col == p.z) || (col == p.w);
    if (!isPos) {
      if (lane == 0) selX[NPOS + got] = col;
      ++got;
    }
    const int owner = (int)(m & 63ull);
    const int slot  = (int)((m >> 6) & 7ull);
    const uint64_t bound = m >> 9;
    uint64_t mynxt = 0;
#pragma unroll
    for (int s = 0; s < 8; ++s) mynxt = (slot == s) ? nxt[s] : mynxt;
    const uint64_t ownnxt =
        (uint64_t)__shfl((unsigned long long)mynxt, owner, 64);
    uint64_t newv;
    if (ownnxt) {                        // wave-uniform: promote cached nxt
      newv = ownnxt;
    } else {                             // cooperative rebuild (rare)
      const int thr = (owner << 3) | slot;
      uint64_t v = 0;
      if (lane < 32) {
        const int col2 = ((lane >> 2) << 11) + (thr << 2) + (lane & 3);
        uint32_t o0, o1;
        tf2x32((uint32_t)(rbase + col2), (uint32_t)(rbase + col2) + 0x2000000u, o0, o1);
        v = mkcomp(hi ? o1 : o0, col2);
        if (v >= bound) v = 0;
      }
#pragma unroll
      for (int o = 32; o; o >>= 1) {
        const uint64_t y = (uint64_t)__shfl_xor((unsigned long long)v, o, 64);
        if (y > v) v = y;
      }
      newv = v;
    }
    if (lane == owner) {
#pragma unroll
      for (int s = 0; s < 8; ++s)
        if (slot == s) { cur[s] = newv; nxt[s] = 0; }
    }
  }
}

// ---------------- kernel 2: select + sim + BCE ----------------
__global__ __launch_bounds__(T2, 2) void select_sim(
    const float* __restrict__ feat, const float* __restrict__ proto,
    const uint4* __restrict__ cand, const int4* __restrict__ posIdx,
    float* __restrict__ row_ws) {
  __shared__ uint32_t candL[T1][2];
  __shared__ uint32_t candH[T1][2];
  __shared__ int selL[NSEL], selH[NSEL];
  __shared__ float ffL[D], ffH[D];
  __shared__ float normL, normH;
  __shared__ float bces[2 * NSEL];

  const int tid = threadIdx.x;
  const int r = blockIdx.x;
  const int rbase = r * C;

  const uint4 cd0 = cand[(size_t)r * T1 + tid];
  const uint4 cd1 = cand[(size_t)r * T1 + T2 + tid];
  candL[tid][0] = cd0.x;      candL[tid][1] = cd0.y;
  candH[tid][0] = cd0.z;      candH[tid][1] = cd0.w;
  candL[T2 + tid][0] = cd1.x; candL[T2 + tid][1] = cd1.y;
  candH[T2 + tid][0] = cd1.z; candH[T2 + tid][1] = cd1.w;
  const int4 pL = posIdx[r * 2];
  const int4 pH = posIdx[r * 2 + 1];
  if (tid == 0) { selL[0] = pL.x; selL[1] = pL.y; selL[2] = pL.z; selL[3] = pL.w; }
  if (tid == 1) { selH[0] = pH.x; selH[1] = pH.y; selH[2] = pH.z; selH[3] = pH.w; }
  __syncthreads();

  const int wv = tid >> 6;
  if (wv == 0) {
    wave_select8(candL, selL, rbase, 0, pL);
  } else if (wv == 1) {
    wave_select8(candH, selH, rbase, 1, pH);
  } else if (wv == 2) {
    const int l = tid & 63;
    const float a = feat[(size_t)r * D + l];
    const float b = feat[(size_t)r * D + 64 + l];
    ffL[l] = a; ffL[64 + l] = b;
    float s = a * a + b * b;
#pragma unroll
    for (int o = 32; o; o >>= 1) s += __shfl_xor(s, o, 64);
    if (l == 0) normL = s;
  } else {
    const int l = tid & 63;
    const float a = feat[((size_t)r + HALF) * D + l];
    const float b = feat[((size_t)r + HALF) * D + 64 + l];
    ffH[l] = a; ffH[64 + l] = b;
    float s = a * a + b * b;
#pragma unroll
    for (int o = 32; o; o >>= 1) s += __shfl_xor(s, o, 64);
    if (l == 0) normH = s;
  }
  __syncthreads();

  if (tid < 4 * 2 * NSEL) {
    const int ci = tid >> 2;            // 0..47
    const int k  = tid & 3;
    const bool isH = ci >= NSEL;
    const int g = isH ? ci - NSEL : ci;
    const int c = isH ? selH[g] : selL[g];
    const float* ff = isH ? ffH : ffL;
    const float4* pc = reinterpret_cast<const float4*>(proto + (size_t)c * D);
    float fp = 0.f, pp = 0.f;
#pragma unroll
    for (int qq = 0; qq < 8; ++qq) {
      const float4 pv = pc[k * 8 + qq];
      const int d0 = k * 32 + qq * 4;
      fp += ff[d0] * pv.x + ff[d0 + 1] * pv.y + ff[d0 + 2] * pv.z + ff[d0 + 3] * pv.w;
      pp += pv.x * pv.x + pv.y * pv.y + pv.z * pv.z + pv.w * pv.w;
    }
    fp += __shfl_xor(fp, 1, 64); pp += __shfl_xor(pp, 1, 64);
    fp += __shfl_xor(fp, 2, 64); pp += __shfl_xor(pp, 2, 64);
    if (k == 0) {
      const float x = (isH ? normH : normL) * pp;
      float rn = rsqrtf(x);
      rn = rn * (1.5f - 0.5f * x * rn * rn);   // 1 NR step for accuracy
      const float l = fp * rn * 10.0f;          // /TEMP, TEMP=0.1
      const float tgt = (g < NPOS) ? 0.25f : 0.0f;
      bces[ci] = fmaxf(l, 0.f) - l * tgt + __logf(1.0f + __expf(-fabsf(l)));
    }
  }
  __syncthreads();
  if (tid < 2) {
    float s = 0.f;
    const int base = tid * NSEL;
#pragma unroll
    for (int i = 0; i < NSEL; ++i) s += bces[base + i];
    row_ws[tid ? (r + HALF) : r] = s * (1.0f / NSEL);
  }
}

__global__ __launch_bounds__(T2) void supcon_reduce(
    const float* __restrict__ ws, float* __restrict__ out) {
  __shared__ float red[T2];
  const int tid = threadIdx.x;
  float s = 0.f;
#pragma unroll
  for (int j = 0; j < BS / T2; ++j) s += ws[j * T2 + tid];
  red[tid] = s;
  __syncthreads();
  for (int o = T2 / 2; o > 0; o >>= 1) {
    if (tid < o) red[tid] += red[tid + o];
    __syncthreads();
  }
  if (tid == 0) out[0] = red[0] * (1.0f / BS);
}

extern "C" void kernel_launch(void* const* d_in, const int* in_sizes, int n_in,
                              void* d_out, int out_size, void* d_ws, size_t ws_size,
                              hipStream_t stream) {
  (void)in_sizes; (void)n_in; (void)out_size; (void)ws_size;
  const float* feat  = (const float*)d_in[0];
  const float* proto = (const float*)d_in[1];
  const int*   lab   = (const int*)d_in[2];
  float* out = (float*)d_out;
  // ws layout: [0,16K): row_ws float[4096]; [16K,144K): posIdx int4[4096];
  //            [256K,256K+16M): cand uint4[2048*512]
  float* ws     = (float*)d_ws;
  int4*  posIdx = (int4*)((char*)d_ws + (16 << 10));
  uint4* cand   = (uint4*)((char*)d_ws + (256 << 10));

  hash_topk <<<dim3(HALF), dim3(T1), 0, stream>>>(lab, cand, posIdx);
  select_sim<<<dim3(HALF), dim3(T2), 0, stream>>>(feat, proto, cand, posIdx, ws);
  supcon_reduce<<<dim3(1), dim3(T2), 0, stream>>>(ws, out);
}